// Round 17
// baseline (802.997 us; speedup 1.0000x reference)
//
#include <hip/hip_runtime.h>

#define KOFF 27
#define MPAIR 100000
#define NPAIR (KOFF * MPAIR)        // 2,700,000
#define NIN 200000
#define NOUT 400000
#define CIN 32
#define COUT 32

#define ROWS_PER_BIN 256
#define NBIN 1563                   // ceil(400000/256)
#define CAPB 3072                   // per-bin capacity (avg 1728, +32 sigma)
#define BPB 8192
#define SPILL_CAP 65536

// ---------- workspace layout (bytes) ----------
// gbin      @ 0          : 1563*4 -> pad 8192
// spill_cnt @ 8192       : 256
// spill     @ 8448       : 65536*8 = 524,288 -> 532,736
// binned    @ 532,736    : 1563*3072*4 = 19,206,144 -> 19,738,880
// feats16   @ 19,738,880 : 200000*32*2 = 12,800,000 -> 32,538,880
#define O_SPCNT   ((size_t)8192)
#define O_SPILL   ((size_t)8448)
#define O_BINNED  ((size_t)532736)
#define O_F16     ((size_t)19738880)
#define WS_NEED   ((size_t)32538880)

typedef unsigned int uint4n __attribute__((ext_vector_type(4)));

__device__ __forceinline__ unsigned int bf16pair(float a, float b) {
    unsigned int ua = __float_as_uint(a), ub = __float_as_uint(b);
    ua = (ua + 0x7fffu + ((ua >> 16) & 1u)) >> 16;   // RNE
    ub = (ub + 0x7fffu + ((ub >> 16) & 1u)) >> 16;
    return ua | (ub << 16);
}
__device__ __forceinline__ float bf2f(unsigned short v) {
    return __uint_as_float(((unsigned int)v) << 16);
}

// ---------- Phase 0: feats f32 -> bf16 ----------
__global__ __launch_bounds__(256) void cvt_kernel(
    const float* __restrict__ feats, unsigned short* __restrict__ f16)
{
    int i = blockIdx.x * 256 + threadIdx.x;
    if (i >= NIN * CIN / 8) return;
    const float4* src = reinterpret_cast<const float4*>(feats) + i * 2;
    float4 a = src[0], b = src[1];
    uint4n u;
    u.x = bf16pair(a.x, a.y); u.y = bf16pair(a.z, a.w);
    u.z = bf16pair(b.x, b.y); u.w = bf16pair(b.z, b.w);
    reinterpret_cast<uint4n*>(f16)[i] = u;
}

// ---------- Phase 1: multisplit by out-row bin; pack (rl|k|irow) ----------
__global__ __launch_bounds__(256) void bin_kernel(
    const int* __restrict__ in_map, const int* __restrict__ out_map,
    int* __restrict__ gbin, int* __restrict__ binned,
    int* __restrict__ spill_cnt, int2* __restrict__ spill)
{
    __shared__ int lhist[NBIN];
    const int t = threadIdx.x;
    const int base = blockIdx.x * BPB;

    for (int c = t; c < NBIN; c += 256) lhist[c] = 0;
    __syncthreads();

    for (int i = t; i < BPB; i += 256) {
        int p = base + i;
        if (p < NPAIR) atomicAdd(&lhist[out_map[p] >> 8], 1);
    }
    __syncthreads();

    for (int c = t; c < NBIN; c += 256) {
        int cnt = lhist[c];
        lhist[c] = (cnt > 0) ? atomicAdd(&gbin[c], cnt) : 0;  // chunk base
    }
    __syncthreads();

    for (int i = t; i < BPB; i += 256) {
        int p = base + i;
        if (p >= NPAIR) continue;
        int row  = out_map[p];
        int irow = in_map[p];
        int k    = p / MPAIR;
        int bin  = row >> 8;
        // rl(8b @23..30) | k(5b @18..22) | irow(18b @0..17): bit31 unused -> sign-safe
        int val  = ((row & 255) << 23) | (k << 18) | irow;
        int pos = atomicAdd(&lhist[bin], 1);
        if (pos < CAPB) {
            binned[(size_t)bin * CAPB + pos] = val;
        } else {
            int o = atomicAdd(spill_cnt, 1);
            if (o < SPILL_CAP) spill[o] = make_int2(row, p);
        }
    }
}

// ---------- Phase 2: FUSED gather+matvec (no per_off round-trip) ----------
// Lane = output channel. Per contributor: 64B coalesced feats16 group-read
// (random across groups — the latency-bound part, same pattern gather3 proved
// at 13% VALU), 32 shfl broadcasts + 32 coalesced L2-hot f32 weight loads +
// 32 FMAs (4 chains) hidden under that latency.
__global__ __launch_bounds__(256) void gmv_kernel(
    const unsigned short* __restrict__ f16, const float* __restrict__ weight,
    const int* __restrict__ gbin, const int* __restrict__ binned,
    float* __restrict__ out)
{
    __shared__ int sorted[CAPB];             // 12 KB
    __shared__ int cnt[ROWS_PER_BIN];
    __shared__ int scn[ROWS_PER_BIN];
    __shared__ int cur[ROWS_PER_BIN];

    const int bin = blockIdx.x;
    const int t = threadIdx.x;
    const int n = min(gbin[bin], CAPB);
    const int* mybin = binned + (size_t)bin * CAPB;

    cnt[t] = 0;
    __syncthreads();

    for (int i = t; i < n; i += 256)
        atomicAdd(&cnt[(mybin[i] >> 23) & 255], 1);
    __syncthreads();

    scn[t] = cnt[t];
    __syncthreads();
#pragma unroll
    for (int off = 1; off < 256; off <<= 1) {
        int v = (t >= off) ? scn[t - off] : 0;
        __syncthreads();
        scn[t] += v;
        __syncthreads();
    }
    cur[t] = scn[t] - cnt[t];
    __syncthreads();

    for (int i = t; i < n; i += 256) {
        int v = mybin[i];
        int pos = atomicAdd(&cur[(v >> 23) & 255], 1);
        sorted[pos] = v & 0x7FFFFF;          // k(5b) | irow(18b)
    }
    __syncthreads();

    const int g = t >> 5, lane = t & 31;
    for (int r = g; r < ROWS_PER_BIN; r += 8) {
        int grow = (bin << 8) + r;
        if (grow >= NOUT) break;
        int s1 = scn[r], s0v = s1 - cnt[r];
        float a0 = 0.f, a1 = 0.f, a2 = 0.f, a3 = 0.f;   // 4 chains across all contributors
        for (int i = s0v; i < s1; ++i) {
            int e = sorted[i];               // LDS broadcast (uniform in group)
            int irow = e & 0x3FFFF;
            int k = (e >> 18) & 31;
            float fv = bf2f(f16[(size_t)irow * CIN + lane]);  // 64B group read
            const float* wk = weight + (size_t)k * (CIN * COUT);
#pragma unroll
            for (int ci = 0; ci < CIN; ci += 4) {
                a0 = fmaf(__shfl(fv, ci + 0, 32), wk[(ci + 0) * COUT + lane], a0);
                a1 = fmaf(__shfl(fv, ci + 1, 32), wk[(ci + 1) * COUT + lane], a1);
                a2 = fmaf(__shfl(fv, ci + 2, 32), wk[(ci + 2) * COUT + lane], a2);
                a3 = fmaf(__shfl(fv, ci + 3, 32), wk[(ci + 3) * COUT + lane], a3);
            }
        }
        out[(size_t)grow * COUT + lane] = (a0 + a1) + (a2 + a3);  // zeros if empty
    }
}

// ---------- Phase 3: rare bin overflow, recompute + f32 atomics ----------
__global__ __launch_bounds__(256) void spill_kernel(
    const float* __restrict__ feats, const float* __restrict__ weight,
    const int* __restrict__ in_map,
    const int* __restrict__ spill_cnt, const int2* __restrict__ spill,
    float* __restrict__ out)
{
    int n = min(*spill_cnt, SPILL_CAP);
    for (int i = blockIdx.x * blockDim.x + threadIdx.x; i < n * 32;
         i += gridDim.x * blockDim.x) {
        int idx = i >> 5, co = i & 31;
        int2 s = spill[idx];
        int row = s.x;
        int p   = s.y;
        int k   = p / MPAIR;
        int irow = in_map[p];
        const float* f  = feats + (size_t)irow * CIN;
        const float* wk = weight + (size_t)k * (CIN * COUT);
        float acc = 0.f;
#pragma unroll
        for (int ci = 0; ci < CIN; ++ci)
            acc = fmaf(f[ci], wk[ci * COUT + co], acc);
        atomicAdd(&out[(size_t)row * COUT + co], acc);
    }
}

// ---------- last-resort fallback (tiny ws): R1 atomic scatter ----------
__global__ __launch_bounds__(256) void spconvt_fallback(
    const float* __restrict__ feats, const float* __restrict__ weight,
    const int* __restrict__ in_map, const int* __restrict__ out_map,
    float* __restrict__ out)
{
    const int k = blockIdx.y;
    const int m = blockIdx.x * blockDim.x + threadIdx.x;
    const bool active = (m < MPAIR);
    const int mm = active ? m : (MPAIR - 1);
    const int pair = k * MPAIR + mm;
    const int in_row = in_map[pair];
    const int out_row = out_map[pair];
    const float4* frow = reinterpret_cast<const float4*>(feats + (size_t)in_row * CIN);
    float4 f4[8];
#pragma unroll
    for (int i = 0; i < 8; ++i) f4[i] = frow[i];
    const float* f = reinterpret_cast<const float*>(f4);
    float acc[COUT];
#pragma unroll
    for (int i = 0; i < COUT; ++i) acc[i] = 0.f;
    const float* wk = weight + (size_t)k * (CIN * COUT);
#pragma unroll
    for (int ci = 0; ci < CIN; ++ci) {
        const float fv = f[ci];
#pragma unroll
        for (int co = 0; co < COUT; ++co)
            acc[co] = fmaf(fv, wk[ci * COUT + co], acc[co]);
    }
    if (active) {
        float* orow = out + (size_t)out_row * COUT;
#pragma unroll
        for (int co = 0; co < COUT; ++co) atomicAdd(orow + co, acc[co]);
    }
}

extern "C" void kernel_launch(void* const* d_in, const int* in_sizes, int n_in,
                              void* d_out, int out_size, void* d_ws, size_t ws_size,
                              hipStream_t stream) {
    const float* feats  = (const float*)d_in[0];
    const float* weight = (const float*)d_in[1];
    const int* in_map   = (const int*)d_in[2];
    const int* out_map  = (const int*)d_in[3];
    float* out          = (float*)d_out;
    char* ws            = (char*)d_ws;

    if (ws_size >= WS_NEED) {
        int* gbin           = (int*)(ws);
        int* spill_cnt      = (int*)(ws + O_SPCNT);
        int2* spill         = (int2*)(ws + O_SPILL);
        int* binned         = (int*)(ws + O_BINNED);
        unsigned short* f16 = (unsigned short*)(ws + O_F16);

        (void)hipMemsetAsync(ws, 0, O_SPILL, stream);   // gbin + spill_cnt

        cvt_kernel<<<dim3((NIN * CIN / 8 + 255) / 256), dim3(256), 0, stream>>>(
            feats, f16);

        bin_kernel<<<dim3((NPAIR + BPB - 1) / BPB), dim3(256), 0, stream>>>(
            in_map, out_map, gbin, binned, spill_cnt, spill);

        gmv_kernel<<<dim3(NBIN), dim3(256), 0, stream>>>(
            f16, weight, gbin, binned, out);

        spill_kernel<<<dim3(64), dim3(256), 0, stream>>>(
            feats, weight, in_map, spill_cnt, spill, out);
    } else {
        (void)hipMemsetAsync(d_out, 0, (size_t)out_size * sizeof(float), stream);
        spconvt_fallback<<<dim3((MPAIR + 255) / 256, KOFF), dim3(256), 0, stream>>>(
            feats, weight, in_map, out_map, out);
    }
}

// Round 18
// 300.928 us; speedup vs baseline: 2.6684x; 2.6684x over previous
//
#include <hip/hip_runtime.h>

#define KOFF 27
#define MPAIR 100000
#define NPAIR (KOFF * MPAIR)        // 2,700,000
#define NIN 200000
#define NOUT 400000
#define CIN 32
#define COUT 32

#define ROWS_PER_BIN 256
#define NBIN ((NOUT + ROWS_PER_BIN - 1) / ROWS_PER_BIN)   // 1563
#define CAPB 3072                   // per-bin capacity (avg 1728, +32 sigma)
#define BPB 8192                    // pairs per bin_kernel block
#define SPILL_CAP 65536

// ---------- workspace layout (bytes) ----------
// gbin      @ 0          : NBIN*4 -> pad 8192
// spill_cnt @ 8192       : 256
// spill     @ 8448       : SPILL_CAP*8 = 524,288        -> end 532,736
// binned    @ 532,736    : NBIN*CAPB*4 = 19,206,144     -> end 19,738,880
// per_off   @ 19,738,880 : 2.7M*32*2  = 172,800,000     -> end 192,538,880
// feats16   @ 192,538,880: 200000*32*2 = 12,800,000     -> end 205,338,880
#define O_SPCNT   ((size_t)8192)
#define O_SPILL   ((size_t)8448)
#define O_BINNED  ((size_t)532736)
#define O_PEROFF  ((size_t)19738880)
#define O_F16     ((size_t)192538880)
#define WS_NEED   ((size_t)205338880)

typedef unsigned int uint4n __attribute__((ext_vector_type(4)));

__device__ __forceinline__ unsigned int bf16pair(float a, float b) {
    unsigned int ua = __float_as_uint(a), ub = __float_as_uint(b);
    ua = (ua + 0x7fffu + ((ua >> 16) & 1u)) >> 16;   // RNE
    ub = (ub + 0x7fffu + ((ub >> 16) & 1u)) >> 16;
    return ua | (ub << 16);
}
__device__ __forceinline__ float bf2f(unsigned short v) {
    return __uint_as_float(((unsigned int)v) << 16);
}
__device__ __forceinline__ float bf2f_lo(unsigned int w) {
    return __uint_as_float(w << 16);
}
__device__ __forceinline__ float bf2f_hi(unsigned int w) {
    return __uint_as_float(w & 0xFFFF0000u);
}

// ---------- Phase 0: feats f32 -> bf16 ----------
__global__ __launch_bounds__(256) void cvt_kernel(
    const float* __restrict__ feats, unsigned short* __restrict__ f16)
{
    int i = blockIdx.x * 256 + threadIdx.x;          // one thread = 8 elements
    if (i >= NIN * CIN / 8) return;
    const float4* src = reinterpret_cast<const float4*>(feats) + i * 2;
    float4 a = src[0], b = src[1];
    uint4n u;
    u.x = bf16pair(a.x, a.y); u.y = bf16pair(a.z, a.w);
    u.z = bf16pair(b.x, b.y); u.w = bf16pair(b.z, b.w);
    reinterpret_cast<uint4n*>(f16)[i] = u;
}

// ---------- Phase 1: multisplit pair ids by output-row bin ----------
__global__ __launch_bounds__(256) void bin_kernel(
    const int* __restrict__ out_map,
    int* __restrict__ gbin, int* __restrict__ binned,
    int* __restrict__ spill_cnt, int2* __restrict__ spill)
{
    __shared__ int lhist[NBIN];              // count, then running cursor
    const int t = threadIdx.x;
    const int base = blockIdx.x * BPB;

    for (int c = t; c < NBIN; c += 256) lhist[c] = 0;
    __syncthreads();

    for (int i = t; i < BPB; i += 256) {
        int p = base + i;
        if (p < NPAIR) atomicAdd(&lhist[out_map[p] >> 8], 1);
    }
    __syncthreads();

    for (int c = t; c < NBIN; c += 256) {
        int cnt = lhist[c];
        lhist[c] = (cnt > 0) ? atomicAdd(&gbin[c], cnt) : 0;  // chunk base
    }
    __syncthreads();

    for (int i = t; i < BPB; i += 256) {
        int p = base + i;
        if (p >= NPAIR) continue;
        int row = out_map[p];
        int bin = row >> 8;
        int val = ((row & 255) << 22) | p;
        int pos = atomicAdd(&lhist[bin], 1);
        if (pos < CAPB) {
            binned[(size_t)bin * CAPB + pos] = val;
        } else {
            int o = atomicAdd(spill_cnt, 1);
            if (o < SPILL_CAP) spill[o] = make_int2(row, p);
        }
    }
}

// ---------- Phase 2: per-pair matvec, bf16 feats gather, plain stores ----------
__global__ __launch_bounds__(256) void mv_kernel(
    const unsigned short* __restrict__ f16, const float* __restrict__ weight,
    const int* __restrict__ in_map, unsigned short* __restrict__ per_off)
{
    const int k = blockIdx.y;                 // wave-uniform -> SGPR weights
    const int m = blockIdx.x * 256 + threadIdx.x;
    if (m >= MPAIR) return;
    const int p = k * MPAIR + m;
    const int in_row = in_map[p];

    // 64B random gather
    const uint4n* frow = reinterpret_cast<const uint4n*>(f16 + (size_t)in_row * CIN);
    uint4n q0 = frow[0], q1 = frow[1], q2 = frow[2], q3 = frow[3];

    float f[CIN];
    f[0] = bf2f_lo(q0.x);  f[1] = bf2f_hi(q0.x);
    f[2] = bf2f_lo(q0.y);  f[3] = bf2f_hi(q0.y);
    f[4] = bf2f_lo(q0.z);  f[5] = bf2f_hi(q0.z);
    f[6] = bf2f_lo(q0.w);  f[7] = bf2f_hi(q0.w);
    f[8] = bf2f_lo(q1.x);  f[9] = bf2f_hi(q1.x);
    f[10] = bf2f_lo(q1.y); f[11] = bf2f_hi(q1.y);
    f[12] = bf2f_lo(q1.z); f[13] = bf2f_hi(q1.z);
    f[14] = bf2f_lo(q1.w); f[15] = bf2f_hi(q1.w);
    f[16] = bf2f_lo(q2.x); f[17] = bf2f_hi(q2.x);
    f[18] = bf2f_lo(q2.y); f[19] = bf2f_hi(q2.y);
    f[20] = bf2f_lo(q2.z); f[21] = bf2f_hi(q2.z);
    f[22] = bf2f_lo(q2.w); f[23] = bf2f_hi(q2.w);
    f[24] = bf2f_lo(q3.x); f[25] = bf2f_hi(q3.x);
    f[26] = bf2f_lo(q3.y); f[27] = bf2f_hi(q3.y);
    f[28] = bf2f_lo(q3.z); f[29] = bf2f_hi(q3.z);
    f[30] = bf2f_lo(q3.w); f[31] = bf2f_hi(q3.w);

    float acc[COUT];
#pragma unroll
    for (int i = 0; i < COUT; ++i) acc[i] = 0.f;

    const float* wk = weight + (size_t)k * (CIN * COUT);
#pragma unroll
    for (int ci = 0; ci < CIN; ++ci) {
        const float fv = f[ci];
#pragma unroll
        for (int co = 0; co < COUT; ++co)
            acc[co] = fmaf(fv, wk[ci * COUT + co], acc[co]);
    }

    uint4n u[4];
#pragma unroll
    for (int j = 0; j < 4; ++j) {
        u[j].x = bf16pair(acc[8 * j + 0], acc[8 * j + 1]);
        u[j].y = bf16pair(acc[8 * j + 2], acc[8 * j + 3]);
        u[j].z = bf16pair(acc[8 * j + 4], acc[8 * j + 5]);
        u[j].w = bf16pair(acc[8 * j + 6], acc[8 * j + 7]);
    }
    uint4n* dst = reinterpret_cast<uint4n*>(per_off + (size_t)p * COUT);
#pragma unroll
    for (int j = 0; j < 4; ++j) dst[j] = u[j];       // plain: L2 write-combines
}

// ---------- Phase 3: per-bin counting-sort + ILP4 register-accumulate gather ----------
__global__ __launch_bounds__(256) void gather3_kernel(
    const unsigned short* __restrict__ per_off,
    const int* __restrict__ gbin, const int* __restrict__ binned,
    float* __restrict__ out)
{
    __shared__ int sorted[CAPB];             // 12 KB
    __shared__ int cnt[ROWS_PER_BIN];
    __shared__ int scn[ROWS_PER_BIN];
    __shared__ int cur[ROWS_PER_BIN];

    const int bin = blockIdx.x;
    const int t = threadIdx.x;
    const int n = min(gbin[bin], CAPB);
    const int* mybin = binned + (size_t)bin * CAPB;

    cnt[t] = 0;
    __syncthreads();

    for (int i = t; i < n; i += 256)
        atomicAdd(&cnt[(mybin[i] >> 22) & 255], 1);
    __syncthreads();

    scn[t] = cnt[t];
    __syncthreads();
#pragma unroll
    for (int off = 1; off < 256; off <<= 1) {
        int v = (t >= off) ? scn[t - off] : 0;
        __syncthreads();
        scn[t] += v;
        __syncthreads();
    }
    cur[t] = scn[t] - cnt[t];
    __syncthreads();

    for (int i = t; i < n; i += 256) {
        int v = mybin[i];
        int pos = atomicAdd(&cur[(v >> 22) & 255], 1);
        sorted[pos] = v & 0x3FFFFF;
    }
    __syncthreads();

    const int g = t >> 5, lane = t & 31;
    for (int r = g; r < ROWS_PER_BIN; r += 8) {
        int grow = (bin << 8) + r;
        if (grow >= NOUT) break;
        int s1 = scn[r], s0 = s1 - cnt[r];
        float a0 = 0.f, a1 = 0.f, a2 = 0.f, a3 = 0.f;
        int i = s0;
        for (; i + 4 <= s1; i += 4) {
            int p0 = sorted[i], p1 = sorted[i + 1], p2 = sorted[i + 2], p3 = sorted[i + 3];
            a0 += bf2f(per_off[(size_t)p0 * COUT + lane]);
            a1 += bf2f(per_off[(size_t)p1 * COUT + lane]);
            a2 += bf2f(per_off[(size_t)p2 * COUT + lane]);
            a3 += bf2f(per_off[(size_t)p3 * COUT + lane]);
        }
        for (; i < s1; ++i)
            a0 += bf2f(per_off[(size_t)sorted[i] * COUT + lane]);
        out[(size_t)grow * COUT + lane] = (a0 + a1) + (a2 + a3);
    }
}

// ---------- Phase 4: statistically-rare bin overflow, recompute + atomics ----------
__global__ __launch_bounds__(256) void spill_kernel(
    const float* __restrict__ feats, const float* __restrict__ weight,
    const int* __restrict__ in_map,
    const int* __restrict__ spill_cnt, const int2* __restrict__ spill,
    float* __restrict__ out)
{
    int n = min(*spill_cnt, SPILL_CAP);
    for (int i = blockIdx.x * blockDim.x + threadIdx.x; i < n * 32;
         i += gridDim.x * blockDim.x) {
        int idx = i >> 5, co = i & 31;
        int2 s = spill[idx];
        int row = s.x;
        int p   = s.y;
        int k   = p / MPAIR;
        int irow = in_map[p];
        const float* f  = feats + (size_t)irow * CIN;
        const float* wk = weight + (size_t)k * (CIN * COUT);
        float acc = 0.f;
#pragma unroll
        for (int ci = 0; ci < CIN; ++ci)
            acc = fmaf(f[ci], wk[ci * COUT + co], acc);
        atomicAdd(&out[(size_t)row * COUT + co], acc);
    }
}

// ---------- last-resort fallback (tiny ws): R1 atomic scatter ----------
__global__ __launch_bounds__(256) void spconvt_fallback(
    const float* __restrict__ feats, const float* __restrict__ weight,
    const int* __restrict__ in_map, const int* __restrict__ out_map,
    float* __restrict__ out)
{
    const int k = blockIdx.y;
    const int m = blockIdx.x * blockDim.x + threadIdx.x;
    const bool active = (m < MPAIR);
    const int mm = active ? m : (MPAIR - 1);
    const int pair = k * MPAIR + mm;
    const int in_row = in_map[pair];
    const int out_row = out_map[pair];
    const float4* frow = reinterpret_cast<const float4*>(feats + (size_t)in_row * CIN);
    float4 f4[8];
#pragma unroll
    for (int i = 0; i < 8; ++i) f4[i] = frow[i];
    const float* f = reinterpret_cast<const float*>(f4);
    float acc[COUT];
#pragma unroll
    for (int i = 0; i < COUT; ++i) acc[i] = 0.f;
    const float* wk = weight + (size_t)k * (CIN * COUT);
#pragma unroll
    for (int ci = 0; ci < CIN; ++ci) {
        const float fv = f[ci];
#pragma unroll
        for (int co = 0; co < COUT; ++co)
            acc[co] = fmaf(fv, wk[ci * COUT + co], acc[co]);
    }
    if (active) {
        float* orow = out + (size_t)out_row * COUT;
#pragma unroll
        for (int co = 0; co < COUT; ++co) atomicAdd(orow + co, acc[co]);
    }
}

extern "C" void kernel_launch(void* const* d_in, const int* in_sizes, int n_in,
                              void* d_out, int out_size, void* d_ws, size_t ws_size,
                              hipStream_t stream) {
    const float* feats  = (const float*)d_in[0];
    const float* weight = (const float*)d_in[1];
    const int* in_map   = (const int*)d_in[2];
    const int* out_map  = (const int*)d_in[3];
    float* out          = (float*)d_out;
    char* ws            = (char*)d_ws;

    if (ws_size >= WS_NEED) {
        int* gbin               = (int*)(ws);
        int* spill_cnt          = (int*)(ws + O_SPCNT);
        int2* spill             = (int2*)(ws + O_SPILL);
        int* binned             = (int*)(ws + O_BINNED);
        unsigned short* per_off = (unsigned short*)(ws + O_PEROFF);
        unsigned short* f16     = (unsigned short*)(ws + O_F16);

        (void)hipMemsetAsync(ws, 0, O_SPILL, stream);   // gbin + spill_cnt only

        cvt_kernel<<<dim3((NIN * CIN / 8 + 255) / 256), dim3(256), 0, stream>>>(
            feats, f16);

        bin_kernel<<<dim3((NPAIR + BPB - 1) / BPB), dim3(256), 0, stream>>>(
            out_map, gbin, binned, spill_cnt, spill);

        mv_kernel<<<dim3((MPAIR + 255) / 256, KOFF), dim3(256), 0, stream>>>(
            f16, weight, in_map, per_off);

        gather3_kernel<<<dim3(NBIN), dim3(256), 0, stream>>>(
            per_off, gbin, binned, out);

        spill_kernel<<<dim3(64), dim3(256), 0, stream>>>(
            feats, weight, in_map, spill_cnt, spill, out);
    } else {
        (void)hipMemsetAsync(d_out, 0, (size_t)out_size * sizeof(float), stream);
        spconvt_fallback<<<dim3((MPAIR + 255) / 256, KOFF), dim3(256), 0, stream>>>(
            feats, weight, in_map, out_map, out);
    }
}